// Round 12
// baseline (329.634 us; speedup 1.0000x reference)
//
#include <hip/hip_runtime.h>
#include <math.h>

#define EMBED 1024
#define HEADS 16
#define HD    64
#define NB    4
#define LSEQ  2048

typedef __attribute__((ext_vector_type(8))) short bf16x8;
typedef __attribute__((ext_vector_type(16))) float f32x16;

typedef __attribute__((address_space(1))) void as1_void;
typedef __attribute__((address_space(3))) void as3_void;

#if __has_builtin(__builtin_amdgcn_exp2f)
#define EXP2(x) __builtin_amdgcn_exp2f(x)
#else
#define EXP2(x) exp2f(x)
#endif

__device__ __forceinline__ void gload_lds16(const void* g, void* l) {
    __builtin_amdgcn_global_load_lds((const as1_void*)g, (as3_void*)l, 16, 0, 0);
}

__device__ inline bf16x8 as_bf16x8(uint4 u) {
    union { uint4 u; bf16x8 b; } c; c.u = u; return c.b;
}
// round-to-nearest-even fp32 -> bf16 (raw ushort); finite inputs only
__device__ inline unsigned short bf16r(float x) {
    unsigned u = __float_as_uint(x);
    u += 0x7fffu + ((u >> 16) & 1u);
    return (unsigned short)(u >> 16);
}
__device__ inline float bfh2f(unsigned short h) {
    return __uint_as_float(((unsigned)h) << 16);
}
// split two floats into packed hi/lo bf16 words
__device__ inline void split2(float x, float y, unsigned& hw, unsigned& lw) {
    unsigned short hx = bf16r(x), hy = bf16r(y);
    unsigned short lx = bf16r(x - bfh2f(hx)), ly = bf16r(y - bfh2f(hy));
    hw = (unsigned)hx | ((unsigned)hy << 16);
    lw = (unsigned)lx | ((unsigned)ly << 16);
}

// ---------------------------------------------------------------------------
// Kernel 1: QKV projections as split-bf16 MFMA GEMM (R12 form, unchanged).
// ---------------------------------------------------------------------------
__global__ __launch_bounds__(256, 3) void proj_kernel(
    const float* __restrict__ Xv, const float* __restrict__ Xk, const float* __restrict__ Xq,
    const float* __restrict__ Wv, const float* __restrict__ Wk, const float* __restrict__ Wq,
    const float* __restrict__ Wo,
    unsigned short* __restrict__ Vt, unsigned short* __restrict__ Kp, unsigned short* __restrict__ Qp,
    unsigned short* __restrict__ Woh, unsigned short* __restrict__ Wol)
{
    __shared__ uint4 sXh[128 * 8];   // [token][granule of 8 dims]  16KB
    __shared__ uint4 sXl[128 * 8];   // 16KB
    __shared__ uint4 sWh[64 * 8];    // [e][granule of 8 dims]       8KB
    __shared__ uint4 sWl[64 * 8];    //                              8KB

    const int t = threadIdx.x;

    // ---- z == 3: Wo hi/lo split (former wsplit_kernel) ----
    if (blockIdx.z == 3) {
        int w_id = blockIdx.x + blockIdx.y * 64;          // 0..1023
        int i = w_id * 256 + t;
        float4 v = ((const float4*)Wo)[i];
        ushort4 h4, l4;
        h4.x = bf16r(v.x); l4.x = bf16r(v.x - bfh2f(h4.x));
        h4.y = bf16r(v.y); l4.y = bf16r(v.y - bfh2f(h4.y));
        h4.z = bf16r(v.z); l4.z = bf16r(v.z - bfh2f(h4.z));
        h4.w = bf16r(v.w); l4.w = bf16r(v.w - bfh2f(h4.w));
        ((ushort4*)Woh)[i] = h4;
        ((ushort4*)Wol)[i] = l4;
        return;
    }

    const int lane = t & 63, w = t >> 6;
    const int l5 = lane & 31, hi = lane >> 5;
    const int h  = blockIdx.y;
    const int n  = blockIdx.x >> 4;
    const int l0 = (blockIdx.x & 15) * 128;
    const int p  = blockIdx.z;

    const float QSC = 1.44269504088896341f / 32.0f;
    const float* Xp = (p == 0) ? Xv : (p == 1) ? Xk : Xq;
    const float* Wp = (p == 0) ? Wv : (p == 1) ? Wk : Wq;

    const int frow = t >> 4;        // staging: row group 0..15
    const int fcol = t & 15;        // float4 index within 64-dim row

    // ---- stage X tile: 128 rows x 64 dims fp32 -> hi/lo bf16, swizzled ----
    {
        const float* xb = Xp + ((size_t)(n * LSEQ + l0 + frow)) * EMBED + h * HD + fcol * 4;
        unsigned short* dh = (unsigned short*)sXh;
        unsigned short* dl = (unsigned short*)sXl;
        #pragma unroll
        for (int i = 0; i < 8; ++i) {
            int row = frow + i * 16;
            float4 v = *(const float4*)(xb + (size_t)i * 16 * EMBED);
            int gg = fcol >> 1, s8 = (fcol & 1) * 4;
            int idx = row * 64 + ((gg ^ (row & 7)) * 8) + s8;
            uint2 hv, lv;
            split2(v.x, v.y, hv.x, lv.x);
            split2(v.z, v.w, hv.y, lv.y);
            *(uint2*)(dh + idx) = hv;
            *(uint2*)(dl + idx) = lv;
        }
    }
    // ---- stage W: 64x64 fp32 -> hi/lo bf16, swizzled ----
    #pragma unroll
    for (int i = 0; i < 2; ++i) {
        int u = t + 256 * i;                  // granule 0..511
        int e = u >> 3, g = u & 7;
        const float* wb = Wp + u * 8;
        float4 v0 = *(const float4*)(wb);
        float4 v1 = *(const float4*)(wb + 4);
        uint4 hq, lq;
        split2(v0.x, v0.y, hq.x, lq.x);
        split2(v0.z, v0.w, hq.y, lq.y);
        split2(v1.x, v1.y, hq.z, lq.z);
        split2(v1.z, v1.w, hq.w, lq.w);
        int idx = e * 8 + (g ^ (e & 7));
        sWh[idx] = hq;
        sWl[idx] = lq;
    }
    __syncthreads();

    // ---- MFMA: per wave, 32-token tile x (two 32-wide e-tiles) ----
    f32x16 acc0, acc1;
    #pragma unroll
    for (int i = 0; i < 16; ++i) { acc0[i] = 0.f; acc1[i] = 0.f; }

    const int xrow = w * 32 + l5;
    const int w0r = l5, w1r = 32 + l5;
    #pragma unroll
    for (int kc = 0; kc < 4; ++kc) {
        int gsel = kc * 2 + hi;
        bf16x8 xh = as_bf16x8(sXh[xrow * 8 + (gsel ^ (xrow & 7))]);
        bf16x8 xl = as_bf16x8(sXl[xrow * 8 + (gsel ^ (xrow & 7))]);
        bf16x8 wh0 = as_bf16x8(sWh[w0r * 8 + (gsel ^ (w0r & 7))]);
        bf16x8 wl0 = as_bf16x8(sWl[w0r * 8 + (gsel ^ (w0r & 7))]);
        bf16x8 wh1 = as_bf16x8(sWh[w1r * 8 + (gsel ^ (w1r & 7))]);
        bf16x8 wl1 = as_bf16x8(sWl[w1r * 8 + (gsel ^ (w1r & 7))]);
        if (p == 0) {
            // V^T = W X^T : A=W-frag (rows e), B=X-frag (cols token)
            acc0 = __builtin_amdgcn_mfma_f32_32x32x16_bf16(wh0, xh, acc0, 0, 0, 0);
            acc0 = __builtin_amdgcn_mfma_f32_32x32x16_bf16(wh0, xl, acc0, 0, 0, 0);
            acc0 = __builtin_amdgcn_mfma_f32_32x32x16_bf16(wl0, xh, acc0, 0, 0, 0);
            acc1 = __builtin_amdgcn_mfma_f32_32x32x16_bf16(wh1, xh, acc1, 0, 0, 0);
            acc1 = __builtin_amdgcn_mfma_f32_32x32x16_bf16(wh1, xl, acc1, 0, 0, 0);
            acc1 = __builtin_amdgcn_mfma_f32_32x32x16_bf16(wl1, xh, acc1, 0, 0, 0);
        } else {
            // C = X W^T : A=X-frag (rows token), B=W-frag (cols e)
            acc0 = __builtin_amdgcn_mfma_f32_32x32x16_bf16(xh, wh0, acc0, 0, 0, 0);
            acc0 = __builtin_amdgcn_mfma_f32_32x32x16_bf16(xh, wl0, acc0, 0, 0, 0);
            acc0 = __builtin_amdgcn_mfma_f32_32x32x16_bf16(xl, wh0, acc0, 0, 0, 0);
            acc1 = __builtin_amdgcn_mfma_f32_32x32x16_bf16(xh, wh1, acc1, 0, 0, 0);
            acc1 = __builtin_amdgcn_mfma_f32_32x32x16_bf16(xh, wl1, acc1, 0, 0, 0);
            acc1 = __builtin_amdgcn_mfma_f32_32x32x16_bf16(xl, wh1, acc1, 0, 0, 0);
        }
    }

    // ---- epilogue ----
    if (p == 0) {
        // C rows = e, cols = token (V^T): coalesced Vt [N,H,D,L] stores
        unsigned short* vb = Vt + (((size_t)(n * HEADS + h)) * HD) * LSEQ + l0 + w * 32 + l5;
        #pragma unroll
        for (int r = 0; r < 16; ++r) {
            int er = (r & 3) + 8 * (r >> 2) + 4 * hi;
            vb[(size_t)er * LSEQ]        = bf16r(acc0[r]);
            vb[(size_t)(32 + er) * LSEQ] = bf16r(acc1[r]);
        }
    } else {
        unsigned short* dst = (p == 1) ? Kp : Qp;
        float sc = (p == 2) ? QSC : 1.0f;
        unsigned short* db = dst + (((size_t)(n * HEADS + h)) * LSEQ + l0 + w * 32) * HD;
        #pragma unroll
        for (int r = 0; r < 16; ++r) {
            int tok = (r & 3) + 8 * (r >> 2) + 4 * hi;
            db[(size_t)tok * HD + l5]      = bf16r(acc0[r] * sc);
            db[(size_t)tok * HD + 32 + l5] = bf16r(acc1[r] * sc);
        }
    }
}

// ---------------------------------------------------------------------------
// Kernel 2: MFMA flash attention (R13 form, unchanged — 84us known-good).
// ---------------------------------------------------------------------------
__global__ __launch_bounds__(256, 4) void attn_kernel(
    const unsigned short* __restrict__ Qp, const unsigned short* __restrict__ Kp,
    const unsigned short* __restrict__ Vt,
    unsigned short* __restrict__ AOh, unsigned short* __restrict__ AOl)
{
    __shared__ uint4 sK[2][64 * 8];  // [buf][key][granule]  8KB each
    __shared__ uint4 sV[2][64 * 8];  // [buf][d][key-granule] 8KB each

    const int t = threadIdx.x;
    const int lane = t & 63, w = t >> 6;
    const int l5 = lane & 31, hi = lane >> 5;

    // T1 remap: b -> (xcd, u); group = xcd*8 + (u>>4) owns q-tiles u&15.
    const int b   = blockIdx.x + blockIdx.y * 16 + blockIdx.z * 256;
    const int xcd = b & 7, u = b >> 3;
    const int grp = xcd * 8 + (u >> 4);
    const int n   = grp >> 4, h = grp & 15;
    const int q0  = (u & 15) * 128;

    const size_t hoff = ((size_t)n * HEADS + h) * (size_t)(LSEQ * HD);
    const unsigned short* Kh = Kp + hoff;
    const unsigned short* Vh = Vt + hoff;

    bf16x8 qf[4];
    {
        const uint4* qg = (const uint4*)(Qp + hoff + (size_t)(q0 + w * 32 + l5) * HD);
        #pragma unroll
        for (int kc = 0; kc < 4; ++kc) qf[kc] = as_bf16x8(qg[kc * 2 + hi]);
    }

    f32x16 z16;
    #pragma unroll
    for (int i = 0; i < 16; ++i) z16[i] = 0.f;
    f32x16 Oa0 = z16, Oa1 = z16;
    float ls0 = 0.f, ls1 = 0.f;

    const int r0 = t >> 3;                       // key-row / d-row 0..31
    const int g0 = (t & 7) ^ (r0 & 7);           // swizzled granule
    const uint4* gK = (const uint4*)Kh;
    const uint4* gV = (const uint4*)Vh;          // V^T: 256 uint4 per d-row

    #define STAGE(TILE, BUF)                                                        \
        do {                                                                        \
            int kb_ = (TILE) * 64;                                                  \
            gload_lds16(gK + (size_t)(kb_ + r0) * 8 + g0,        &sK[BUF][t]);      \
            gload_lds16(gK + (size_t)(kb_ + r0 + 32) * 8 + g0,   &sK[BUF][t + 256]);\
            gload_lds16(gV + (size_t)r0 * 256 + (kb_ >> 3) + g0, &sV[BUF][t]);      \
            gload_lds16(gV + (size_t)(r0 + 32) * 256 + (kb_ >> 3) + g0,             \
                        &sV[BUF][t + 256]);                                         \
        } while (0)

    #define COMPUTE(BUF)                                                            \
        do {                                                                        \
            _Pragma("unroll")                                                       \
            for (int tc = 0; tc < 2; ++tc) {                                        \
                int key = tc * 32 + l5;                                             \
                __builtin_amdgcn_s_setprio(1);                                      \
                bf16x8 kf0 = as_bf16x8(sK[BUF][key * 8 + (hi ^ (l5 & 7))]);         \
                f32x16 c = __builtin_amdgcn_mfma_f32_32x32x16_bf16(kf0, qf[0], z16, 0, 0, 0); \
                _Pragma("unroll")                                                   \
                for (int kc = 1; kc < 4; ++kc) {                                    \
                    bf16x8 kf = as_bf16x8(sK[BUF][key * 8 + ((kc * 2 + hi) ^ (l5 & 7))]); \
                    c = __builtin_amdgcn_mfma_f32_32x32x16_bf16(kf, qf[kc], c, 0, 0, 0);  \
                }                                                                   \
                __builtin_amdgcn_s_setprio(0);                                      \
                uint4 pwa, pwb;                                                     \
                {                                                                   \
                    float p0 = EXP2(c[0]),  p1 = EXP2(c[1]);                        \
                    float p2 = EXP2(c[2]),  p3 = EXP2(c[3]);                        \
                    ls0 += p0 + p1; ls1 += p2 + p3;                                 \
                    asm("v_cvt_pk_bf16_f32 %0, %1, %2" : "=v"(pwa.x) : "v"(p0), "v"(p1)); \
                    asm("v_cvt_pk_bf16_f32 %0, %1, %2" : "=v"(pwa.y) : "v"(p2), "v"(p3)); \
                    p0 = EXP2(c[4]);  p1 = EXP2(c[5]);                              \
                    p2 = EXP2(c[6]);  p3 = EXP2(c[7]);                              \
                    ls0 += p0 + p1; ls1 += p2 + p3;                                 \
                    asm("v_cvt_pk_bf16_f32 %0, %1, %2" : "=v"(pwa.z) : "v"(p0), "v"(p1)); \
                    asm("v_cvt_pk_bf16_f32 %0, %1, %2" : "=v"(pwa.w) : "v"(p2), "v"(p3)); \
                    p0 = EXP2(c[8]);  p1 = EXP2(c[9]);                              \
                    p2 = EXP2(c[10]); p3 = EXP2(c[11]);                             \
                    ls0 += p0 + p1; ls1 += p2 + p3;                                 \
                    asm("v_cvt_pk_bf16_f32 %0, %1, %2" : "=v"(pwb.x) : "v"(p0), "v"(p1)); \
                    asm("v_cvt_pk_bf16_f32 %0, %1, %2" : "=v"(pwb.y) : "v"(p2), "v"(p3)); \
                    p0 = EXP2(c[12]); p1 = EXP2(c[13]);                             \
                    p2 = EXP2(c[14]); p3 = EXP2(c[15]);                             \
                    ls0 += p0 + p1; ls1 += p2 + p3;                                 \
                    asm("v_cvt_pk_bf16_f32 %0, %1, %2" : "=v"(pwb.z) : "v"(p0), "v"(p1)); \
                    asm("v_cvt_pk_bf16_f32 %0, %1, %2" : "=v"(pwb.w) : "v"(p2), "v"(p3)); \
                }                                                                   \
                asm("v_permlane32_swap_b32 %0, %1" : "+v"(pwa.x), "+v"(pwa.z));     \
                asm("v_permlane32_swap_b32 %0, %1" : "+v"(pwa.y), "+v"(pwa.w));     \
                asm("v_permlane32_swap_b32 %0, %1" : "+v"(pwb.x), "+v"(pwb.z));     \
                asm("v_permlane32_swap_b32 %0, %1" : "+v"(pwb.y), "+v"(pwb.w));     \
                __builtin_amdgcn_s_setprio(1);                                      \
                {                                                                   \
                    int vg0 = tc * 4 + hi;                                          \
                    bf16x8 pa = as_bf16x8(pwa);                                     \
                    bf16x8 v0 = as_bf16x8(sV[BUF][ l5       * 8 + (vg0 ^ (l5 & 7))]); \
                    Oa0 = __builtin_amdgcn_mfma_f32_32x32x16_bf16(pa, v0, Oa0, 0, 0, 0); \
                    bf16x8 v1 = as_bf16x8(sV[BUF][(32 + l5) * 8 + (vg0 ^ (l5 & 7))]); \
                    Oa1 = __builtin_amdgcn_mfma_f32_32x32x16_bf16(pa, v1, Oa1, 0, 0, 0); \
                    int vg1 = tc * 4 + 2 + hi;                                      \
                    bf16x8 pb = as_bf16x8(pwb);                                     \
                    bf16x8 v2 = as_bf16x8(sV[BUF][ l5       * 8 + (vg1 ^ (l5 & 7))]); \
                    Oa0 = __builtin_amdgcn_mfma_f32_32x32x16_bf16(pb, v2, Oa0, 0, 0, 0); \
                    bf16x8 v3 = as_bf16x8(sV[BUF][(32 + l5) * 8 + (vg1 ^ (l5 & 7))]); \
                    Oa1 = __builtin_amdgcn_mfma_f32_32x32x16_bf16(pb, v3, Oa1, 0, 0, 0); \
                }                                                                   \
                __builtin_amdgcn_s_setprio(0);                                      \
            }                                                                       \
        } while (0)

    STAGE(0, 0);

    for (int tt = 0; tt < LSEQ / 64; tt += 2) {
        STAGE(tt + 1, 1);
        asm volatile("s_waitcnt vmcnt(4)" ::: "memory");
        __builtin_amdgcn_s_barrier();
        COMPUTE(0);
        __builtin_amdgcn_s_barrier();

        if (tt + 2 < LSEQ / 64) {
            STAGE(tt + 2, 0);
            asm volatile("s_waitcnt vmcnt(4)" ::: "memory");
        } else {
            asm volatile("s_waitcnt vmcnt(0)" ::: "memory");
        }
        __builtin_amdgcn_s_barrier();
        COMPUTE(1);
        __builtin_amdgcn_s_barrier();
    }
    #undef STAGE
    #undef COMPUTE

    float lsum = ls0 + ls1;
    lsum += __shfl_xor(lsum, 32);
    float inv = 1.0f / lsum;
    float* sLf = (float*)&sK[0][0];
    if (hi == 0) sLf[w * 32 + l5] = inv;
    __syncthreads();

    unsigned short* hB = AOh + hoff;
    unsigned short* lB = AOl + hoff;
    #pragma unroll
    for (int r = 0; r < 16; ++r) {
        int qr = (r & 3) + 8 * (r >> 2) + 4 * hi;
        float invq = sLf[w * 32 + qr];
        size_t row = (size_t)(q0 + w * 32 + qr) * HD;
        float o0 = Oa0[r] * invq;
        float o1 = Oa1[r] * invq;
        unsigned short h0 = bf16r(o0), h1 = bf16r(o1);
        hB[row +      l5] = h0;
        hB[row + 32 + l5] = h1;
        lB[row +      l5] = bf16r(o0 - bfh2f(h0));
        lB[row + 32 + l5] = bf16r(o1 - bfh2f(h1));
    }
}

// ---------------------------------------------------------------------------
// Kernel 3: output projection, split-bf16 MFMA GEMM.
// R16 (R8 counters: VALU 12.7% / MFMA 24% / occ 22.7% -> latency/occupancy
// bound).  Key observation: the A-operand rows are WAVE-PRIVATE (amr =
// w*32+l5; each wave reads only its own 32 token-rows), so staging A through
// LDS shares nothing — it only adds 4 of 6 barrier-coupled gload_lds/chunk,
// 32KB of LDS, and ties A's memory latency to the block barrier.  Changes:
//  - sA deleted.  A fragments load directly global->VGPR per thread (L2-hit
//    via T1; lanes hi=0/1 read adjacent 16B granules of one 128B row so the
//    ks=0/ks=1 loads split the same 64B lines -> L1-line-perfect).
//  - A ping-pong register prefetch one chunk ahead; chunk loop unrolled x2
//    so the A-buffer selection is compile-time (rule #20, no scratch).
//  - LDS = sB only, 2x8KB.  Staging 2 gload_lds/chunk; counted vmcnt(6)
//    covers {2 B + 4 A} newer ops in flight.
//  - B reads keep the R14 deep swizzle (rows thread-fixed -> free).
// Spill guard: WRITE_SIZE must stay ~32.8MB.
// ---------------------------------------------------------------------------
__global__ __launch_bounds__(256, 4) void outproj_kernel(
    const unsigned short* __restrict__ AOh, const unsigned short* __restrict__ AOl,
    const unsigned short* __restrict__ Woh, const unsigned short* __restrict__ Wol,
    const float* __restrict__ bo, float* __restrict__ out)
{
    __shared__ uint4 sB[2][512];    // [buf][e row 0..63][8 granules] 8KB each

    const int t = threadIdx.x;
    const int lane = t & 63, w = t >> 6;
    const int l5 = lane & 31, hi = lane >> 5;

    // T1 remap: l -> (xcd, u); m-tile = xcd*8 + (u&7), e-tile = u>>3.
    const int bl  = blockIdx.x + blockIdx.y * 64;
    const int xcd = bl & 7, u = bl >> 3;
    const int m0  = (xcd * 8 + (u & 7)) * 128;
    const int e0  = (u >> 3) * 64;
    const int n   = m0 >> 11, l0 = m0 & 2047;

    #define SW(r) (((r) ^ ((r) >> 3)) & 7)

    #define BSTAGE(C, BUF)                                                            \
        do {                                                                          \
            int hh_ = (C) >> 1, hf_ = (C) & 1;                                        \
            const uint4* gBh_ = (const uint4*)(Woh) +                                 \
                (size_t)e0 * 128 + hh_ * 8 + hf_ * 4;                                 \
            const uint4* gBl_ = (const uint4*)(Wol) +                                 \
                (size_t)e0 * 128 + hh_ * 8 + hf_ * 4;                                 \
            _Pragma("unroll")                                                         \
            for (int i_ = 0; i_ < 2; ++i_) {                                          \
                int s_ = t + 256 * i_;                                                \
                int row_ = s_ >> 3, sg_ = (s_ & 7) ^ SW(row_);                        \
                const uint4* src_ = (sg_ < 4 ? gBh_ : gBl_) +                         \
                    (size_t)row_ * 128 + (sg_ & 3);                                   \
                gload_lds16(src_, &sB[BUF][s_]);                                      \
            }                                                                         \
        } while (0)

    const int amr = w * 32 + l5;                 // this thread's A row (fixed)
    const size_t aRow = ((size_t)n * HEADS) * LSEQ * 8 + (size_t)(l0 + amr) * 8;
    const uint4* pAh = (const uint4*)AOh + aRow;
    const uint4* pAl = (const uint4*)AOl + aRow;
    // chunk C: head hh=C>>1 (row offset hh*LSEQ*8), quarter hf=C&1 (+hf*4);
    // ks granule = +ks*2+hi.
    #define ALOAD(C, H0, H1, L0, L1)                                                  \
        do {                                                                          \
            size_t off_ = (size_t)((C) >> 1) * (LSEQ * 8) + ((C) & 1) * 4 + hi;       \
            H0 = as_bf16x8(pAh[off_]);                                                \
            H1 = as_bf16x8(pAh[off_ + 2]);                                            \
            L0 = as_bf16x8(pAl[off_]);                                                \
            L1 = as_bf16x8(pAl[off_ + 2]);                                            \
        } while (0)

    const int swb0 = SW(l5);
    const int swb1 = SW(32 + l5);

    #define OCOMPUTE(BUF, H0, H1, L0, L1)                                             \
        do {                                                                          \
            __builtin_amdgcn_s_setprio(1);                                            \
            _Pragma("unroll")                                                         \
            for (int ks = 0; ks < 2; ++ks) {                                          \
                int gx = ks * 2 + hi;                                                 \
                bf16x8 ah = ks ? H1 : H0;                                             \
                bf16x8 al = ks ? L1 : L0;                                             \
                bf16x8 bh0 = as_bf16x8(sB[BUF][ l5       * 8 + ( gx      ^ swb0)]);   \
                bf16x8 bh1 = as_bf16x8(sB[BUF][(32 + l5) * 8 + ( gx      ^ swb1)]);   \
                bf16x8 bl0 = as_bf16x8(sB[BUF][ l5       * 8 + ((gx + 4) ^ swb0)]);   \
                bf16x8 bl1 = as_bf16x8(sB[BUF][(32 + l5) * 8 + ((gx + 4) ^ swb1)]);   \
                acc0 = __builtin_amdgcn_mfma_f32_32x32x16_bf16(ah, bh0, acc0, 0, 0, 0); \
                acc1 = __builtin_amdgcn_mfma_f32_32x32x16_bf16(ah, bh1, acc1, 0, 0, 0); \
                acc0 = __builtin_amdgcn_mfma_f32_32x32x16_bf16(ah, bl0, acc0, 0, 0, 0); \
                acc1 = __builtin_amdgcn_mfma_f32_32x32x16_bf16(ah, bl1, acc1, 0, 0, 0); \
                acc0 = __builtin_amdgcn_mfma_f32_32x32x16_bf16(al, bh0, acc0, 0, 0, 0); \
                acc1 = __builtin_amdgcn_mfma_f32_32x32x16_bf16(al, bh1, acc1, 0, 0, 0); \
            }                                                                         \
            __builtin_amdgcn_s_setprio(0);                                            \
        } while (0)

    f32x16 acc0, acc1;
    #pragma unroll
    for (int i = 0; i < 16; ++i) { acc0[i] = 0.f; acc1[i] = 0.f; }

    bf16x8 eH0, eH1, eL0, eL1;      // even-chunk A frags
    bf16x8 oH0, oH1, oL0, oL1;      // odd-chunk A frags

    BSTAGE(0, 0);
    ALOAD(0, eH0, eH1, eL0, eL1);

    #pragma unroll 1
    for (int c = 0; c < 32; c += 2) {
        // issue next chunk (odd) while waiting for current (even)
        BSTAGE(c + 1, 1);
        ALOAD(c + 1, oH0, oH1, oL0, oL1);
        asm volatile("s_waitcnt vmcnt(6)" ::: "memory");
        __builtin_amdgcn_s_barrier();
        OCOMPUTE(0, eH0, eH1, eL0, eL1);
        __builtin_amdgcn_s_barrier();

        if (c + 2 < 32) {
            BSTAGE(c + 2, 0);
            ALOAD(c + 2, eH0, eH1, eL0, eL1);
            asm volatile("s_waitcnt vmcnt(6)" ::: "memory");
        } else {
            asm volatile("s_waitcnt vmcnt(0)" ::: "memory");
        }
        __builtin_amdgcn_s_barrier();
        OCOMPUTE(1, oH0, oH1, oL0, oL1);
        __builtin_amdgcn_s_barrier();
    }
    #undef BSTAGE
    #undef ALOAD
    #undef OCOMPUTE
    #undef SW

    float b0 = bo[e0 + l5];
    float b1 = bo[e0 + 32 + l5];
    #pragma unroll
    for (int r = 0; r < 16; ++r) {
        int row = m0 + w * 32 + (r & 3) + 8 * (r >> 2) + 4 * hi;
        float* o = out + (size_t)row * EMBED + e0;
        o[l5]      = acc0[r] + b0;
        o[32 + l5] = acc1[r] + b1;
    }
}

// ---------------------------------------------------------------------------
extern "C" void kernel_launch(void* const* d_in, const int* in_sizes, int n_in,
                              void* d_out, int out_size, void* d_ws, size_t ws_size,
                              hipStream_t stream)
{
    const float* values  = (const float*)d_in[0];
    const float* keys    = (const float*)d_in[1];
    const float* queries = (const float*)d_in[2];
    const float* Wv      = (const float*)d_in[3];
    const float* Wk      = (const float*)d_in[4];
    const float* Wq      = (const float*)d_in[5];
    const float* Wo      = (const float*)d_in[6];
    const float* bo      = (const float*)d_in[7];
    float* out = (float*)d_out;

    const size_t bufElems = (size_t)NB * HEADS * LSEQ * HD;   // 8,388,608
    unsigned short* Qp  = (unsigned short*)d_ws;
    unsigned short* Kp  = Qp  + bufElems;
    unsigned short* Vt  = Kp  + bufElems;
    unsigned short* AOh = Vt  + bufElems;
    unsigned short* AOl = AOh + bufElems;
    unsigned short* Woh = AOl + bufElems;
    unsigned short* Wol = Woh + (size_t)EMBED * EMBED;

    proj_kernel<<<dim3(NB * 16, HEADS, 4), 256, 0, stream>>>(
        values, keys, queries, Wv, Wk, Wq, Wo, Vt, Kp, Qp, Woh, Wol);
    attn_kernel<<<dim3(LSEQ / 128, HEADS, NB), 256, 0, stream>>>(Qp, Kp, Vt, AOh, AOl);
    outproj_kernel<<<dim3(NB * LSEQ / 128, EMBED / 64), 256, 0, stream>>>(AOh, AOl, Woh, Wol, bo, out);
}

// Round 13
// 325.522 us; speedup vs baseline: 1.0126x; 1.0126x over previous
//
#include <hip/hip_runtime.h>
#include <math.h>

#define EMBED 1024
#define HEADS 16
#define HD    64
#define NB    4
#define LSEQ  2048

typedef __attribute__((ext_vector_type(8))) short bf16x8;
typedef __attribute__((ext_vector_type(16))) float f32x16;

typedef __attribute__((address_space(1))) void as1_void;
typedef __attribute__((address_space(3))) void as3_void;

#if __has_builtin(__builtin_amdgcn_exp2f)
#define EXP2(x) __builtin_amdgcn_exp2f(x)
#else
#define EXP2(x) exp2f(x)
#endif

__device__ __forceinline__ void gload_lds16(const void* g, void* l) {
    __builtin_amdgcn_global_load_lds((const as1_void*)g, (as3_void*)l, 16, 0, 0);
}

__device__ inline bf16x8 as_bf16x8(uint4 u) {
    union { uint4 u; bf16x8 b; } c; c.u = u; return c.b;
}
// round-to-nearest-even fp32 -> bf16 (raw ushort); finite inputs only
__device__ inline unsigned short bf16r(float x) {
    unsigned u = __float_as_uint(x);
    u += 0x7fffu + ((u >> 16) & 1u);
    return (unsigned short)(u >> 16);
}
__device__ inline float bfh2f(unsigned short h) {
    return __uint_as_float(((unsigned)h) << 16);
}
// split two floats into packed hi/lo bf16 words
__device__ inline void split2(float x, float y, unsigned& hw, unsigned& lw) {
    unsigned short hx = bf16r(x), hy = bf16r(y);
    unsigned short lx = bf16r(x - bfh2f(hx)), ly = bf16r(y - bfh2f(hy));
    hw = (unsigned)hx | ((unsigned)hy << 16);
    lw = (unsigned)lx | ((unsigned)ly << 16);
}

// ---------------------------------------------------------------------------
// Kernel 1: QKV projections as split-bf16 MFMA GEMM (R12 form, unchanged).
// ---------------------------------------------------------------------------
__global__ __launch_bounds__(256, 3) void proj_kernel(
    const float* __restrict__ Xv, const float* __restrict__ Xk, const float* __restrict__ Xq,
    const float* __restrict__ Wv, const float* __restrict__ Wk, const float* __restrict__ Wq,
    const float* __restrict__ Wo,
    unsigned short* __restrict__ Vt, unsigned short* __restrict__ Kp, unsigned short* __restrict__ Qp,
    unsigned short* __restrict__ Woh, unsigned short* __restrict__ Wol)
{
    __shared__ uint4 sXh[128 * 8];   // [token][granule of 8 dims]  16KB
    __shared__ uint4 sXl[128 * 8];   // 16KB
    __shared__ uint4 sWh[64 * 8];    // [e][granule of 8 dims]       8KB
    __shared__ uint4 sWl[64 * 8];    //                              8KB

    const int t = threadIdx.x;

    // ---- z == 3: Wo hi/lo split (former wsplit_kernel) ----
    if (blockIdx.z == 3) {
        int w_id = blockIdx.x + blockIdx.y * 64;          // 0..1023
        int i = w_id * 256 + t;
        float4 v = ((const float4*)Wo)[i];
        ushort4 h4, l4;
        h4.x = bf16r(v.x); l4.x = bf16r(v.x - bfh2f(h4.x));
        h4.y = bf16r(v.y); l4.y = bf16r(v.y - bfh2f(h4.y));
        h4.z = bf16r(v.z); l4.z = bf16r(v.z - bfh2f(h4.z));
        h4.w = bf16r(v.w); l4.w = bf16r(v.w - bfh2f(h4.w));
        ((ushort4*)Woh)[i] = h4;
        ((ushort4*)Wol)[i] = l4;
        return;
    }

    const int lane = t & 63, w = t >> 6;
    const int l5 = lane & 31, hi = lane >> 5;
    const int h  = blockIdx.y;
    const int n  = blockIdx.x >> 4;
    const int l0 = (blockIdx.x & 15) * 128;
    const int p  = blockIdx.z;

    const float QSC = 1.44269504088896341f / 32.0f;
    const float* Xp = (p == 0) ? Xv : (p == 1) ? Xk : Xq;
    const float* Wp = (p == 0) ? Wv : (p == 1) ? Wk : Wq;

    const int frow = t >> 4;        // staging: row group 0..15
    const int fcol = t & 15;        // float4 index within 64-dim row

    // ---- stage X tile: 128 rows x 64 dims fp32 -> hi/lo bf16, swizzled ----
    {
        const float* xb = Xp + ((size_t)(n * LSEQ + l0 + frow)) * EMBED + h * HD + fcol * 4;
        unsigned short* dh = (unsigned short*)sXh;
        unsigned short* dl = (unsigned short*)sXl;
        #pragma unroll
        for (int i = 0; i < 8; ++i) {
            int row = frow + i * 16;
            float4 v = *(const float4*)(xb + (size_t)i * 16 * EMBED);
            int gg = fcol >> 1, s8 = (fcol & 1) * 4;
            int idx = row * 64 + ((gg ^ (row & 7)) * 8) + s8;
            uint2 hv, lv;
            split2(v.x, v.y, hv.x, lv.x);
            split2(v.z, v.w, hv.y, lv.y);
            *(uint2*)(dh + idx) = hv;
            *(uint2*)(dl + idx) = lv;
        }
    }
    // ---- stage W: 64x64 fp32 -> hi/lo bf16, swizzled ----
    #pragma unroll
    for (int i = 0; i < 2; ++i) {
        int u = t + 256 * i;                  // granule 0..511
        int e = u >> 3, g = u & 7;
        const float* wb = Wp + u * 8;
        float4 v0 = *(const float4*)(wb);
        float4 v1 = *(const float4*)(wb + 4);
        uint4 hq, lq;
        split2(v0.x, v0.y, hq.x, lq.x);
        split2(v0.z, v0.w, hq.y, lq.y);
        split2(v1.x, v1.y, hq.z, lq.z);
        split2(v1.z, v1.w, hq.w, lq.w);
        int idx = e * 8 + (g ^ (e & 7));
        sWh[idx] = hq;
        sWl[idx] = lq;
    }
    __syncthreads();

    // ---- MFMA: per wave, 32-token tile x (two 32-wide e-tiles) ----
    f32x16 acc0, acc1;
    #pragma unroll
    for (int i = 0; i < 16; ++i) { acc0[i] = 0.f; acc1[i] = 0.f; }

    const int xrow = w * 32 + l5;
    const int w0r = l5, w1r = 32 + l5;
    #pragma unroll
    for (int kc = 0; kc < 4; ++kc) {
        int gsel = kc * 2 + hi;
        bf16x8 xh = as_bf16x8(sXh[xrow * 8 + (gsel ^ (xrow & 7))]);
        bf16x8 xl = as_bf16x8(sXl[xrow * 8 + (gsel ^ (xrow & 7))]);
        bf16x8 wh0 = as_bf16x8(sWh[w0r * 8 + (gsel ^ (w0r & 7))]);
        bf16x8 wl0 = as_bf16x8(sWl[w0r * 8 + (gsel ^ (w0r & 7))]);
        bf16x8 wh1 = as_bf16x8(sWh[w1r * 8 + (gsel ^ (w1r & 7))]);
        bf16x8 wl1 = as_bf16x8(sWl[w1r * 8 + (gsel ^ (w1r & 7))]);
        if (p == 0) {
            // V^T = W X^T : A=W-frag (rows e), B=X-frag (cols token)
            acc0 = __builtin_amdgcn_mfma_f32_32x32x16_bf16(wh0, xh, acc0, 0, 0, 0);
            acc0 = __builtin_amdgcn_mfma_f32_32x32x16_bf16(wh0, xl, acc0, 0, 0, 0);
            acc0 = __builtin_amdgcn_mfma_f32_32x32x16_bf16(wl0, xh, acc0, 0, 0, 0);
            acc1 = __builtin_amdgcn_mfma_f32_32x32x16_bf16(wh1, xh, acc1, 0, 0, 0);
            acc1 = __builtin_amdgcn_mfma_f32_32x32x16_bf16(wh1, xl, acc1, 0, 0, 0);
            acc1 = __builtin_amdgcn_mfma_f32_32x32x16_bf16(wl1, xh, acc1, 0, 0, 0);
        } else {
            // C = X W^T : A=X-frag (rows token), B=W-frag (cols e)
            acc0 = __builtin_amdgcn_mfma_f32_32x32x16_bf16(xh, wh0, acc0, 0, 0, 0);
            acc0 = __builtin_amdgcn_mfma_f32_32x32x16_bf16(xh, wl0, acc0, 0, 0, 0);
            acc0 = __builtin_amdgcn_mfma_f32_32x32x16_bf16(xl, wh0, acc0, 0, 0, 0);
            acc1 = __builtin_amdgcn_mfma_f32_32x32x16_bf16(xh, wh1, acc1, 0, 0, 0);
            acc1 = __builtin_amdgcn_mfma_f32_32x32x16_bf16(xh, wl1, acc1, 0, 0, 0);
            acc1 = __builtin_amdgcn_mfma_f32_32x32x16_bf16(xl, wh1, acc1, 0, 0, 0);
        }
    }

    // ---- epilogue ----
    if (p == 0) {
        // C rows = e, cols = token (V^T): coalesced Vt [N,H,D,L] stores
        unsigned short* vb = Vt + (((size_t)(n * HEADS + h)) * HD) * LSEQ + l0 + w * 32 + l5;
        #pragma unroll
        for (int r = 0; r < 16; ++r) {
            int er = (r & 3) + 8 * (r >> 2) + 4 * hi;
            vb[(size_t)er * LSEQ]        = bf16r(acc0[r]);
            vb[(size_t)(32 + er) * LSEQ] = bf16r(acc1[r]);
        }
    } else {
        unsigned short* dst = (p == 1) ? Kp : Qp;
        float sc = (p == 2) ? QSC : 1.0f;
        unsigned short* db = dst + (((size_t)(n * HEADS + h)) * LSEQ + l0 + w * 32) * HD;
        #pragma unroll
        for (int r = 0; r < 16; ++r) {
            int tok = (r & 3) + 8 * (r >> 2) + 4 * hi;
            db[(size_t)tok * HD + l5]      = bf16r(acc0[r] * sc);
            db[(size_t)tok * HD + 32 + l5] = bf16r(acc1[r] * sc);
        }
    }
}

// ---------------------------------------------------------------------------
// Kernel 2: MFMA flash attention (R13 form, unchanged — 84us known-good).
// ---------------------------------------------------------------------------
__global__ __launch_bounds__(256, 4) void attn_kernel(
    const unsigned short* __restrict__ Qp, const unsigned short* __restrict__ Kp,
    const unsigned short* __restrict__ Vt,
    unsigned short* __restrict__ AOh, unsigned short* __restrict__ AOl)
{
    __shared__ uint4 sK[2][64 * 8];  // [buf][key][granule]  8KB each
    __shared__ uint4 sV[2][64 * 8];  // [buf][d][key-granule] 8KB each

    const int t = threadIdx.x;
    const int lane = t & 63, w = t >> 6;
    const int l5 = lane & 31, hi = lane >> 5;

    // T1 remap: b -> (xcd, u); group = xcd*8 + (u>>4) owns q-tiles u&15.
    const int b   = blockIdx.x + blockIdx.y * 16 + blockIdx.z * 256;
    const int xcd = b & 7, u = b >> 3;
    const int grp = xcd * 8 + (u >> 4);
    const int n   = grp >> 4, h = grp & 15;
    const int q0  = (u & 15) * 128;

    const size_t hoff = ((size_t)n * HEADS + h) * (size_t)(LSEQ * HD);
    const unsigned short* Kh = Kp + hoff;
    const unsigned short* Vh = Vt + hoff;

    bf16x8 qf[4];
    {
        const uint4* qg = (const uint4*)(Qp + hoff + (size_t)(q0 + w * 32 + l5) * HD);
        #pragma unroll
        for (int kc = 0; kc < 4; ++kc) qf[kc] = as_bf16x8(qg[kc * 2 + hi]);
    }

    f32x16 z16;
    #pragma unroll
    for (int i = 0; i < 16; ++i) z16[i] = 0.f;
    f32x16 Oa0 = z16, Oa1 = z16;
    float ls0 = 0.f, ls1 = 0.f;

    const int r0 = t >> 3;                       // key-row / d-row 0..31
    const int g0 = (t & 7) ^ (r0 & 7);           // swizzled granule
    const uint4* gK = (const uint4*)Kh;
    const uint4* gV = (const uint4*)Vh;          // V^T: 256 uint4 per d-row

    #define STAGE(TILE, BUF)                                                        \
        do {                                                                        \
            int kb_ = (TILE) * 64;                                                  \
            gload_lds16(gK + (size_t)(kb_ + r0) * 8 + g0,        &sK[BUF][t]);      \
            gload_lds16(gK + (size_t)(kb_ + r0 + 32) * 8 + g0,   &sK[BUF][t + 256]);\
            gload_lds16(gV + (size_t)r0 * 256 + (kb_ >> 3) + g0, &sV[BUF][t]);      \
            gload_lds16(gV + (size_t)(r0 + 32) * 256 + (kb_ >> 3) + g0,             \
                        &sV[BUF][t + 256]);                                         \
        } while (0)

    #define COMPUTE(BUF)                                                            \
        do {                                                                        \
            _Pragma("unroll")                                                       \
            for (int tc = 0; tc < 2; ++tc) {                                        \
                int key = tc * 32 + l5;                                             \
                __builtin_amdgcn_s_setprio(1);                                      \
                bf16x8 kf0 = as_bf16x8(sK[BUF][key * 8 + (hi ^ (l5 & 7))]);         \
                f32x16 c = __builtin_amdgcn_mfma_f32_32x32x16_bf16(kf0, qf[0], z16, 0, 0, 0); \
                _Pragma("unroll")                                                   \
                for (int kc = 1; kc < 4; ++kc) {                                    \
                    bf16x8 kf = as_bf16x8(sK[BUF][key * 8 + ((kc * 2 + hi) ^ (l5 & 7))]); \
                    c = __builtin_amdgcn_mfma_f32_32x32x16_bf16(kf, qf[kc], c, 0, 0, 0);  \
                }                                                                   \
                __builtin_amdgcn_s_setprio(0);                                      \
                uint4 pwa, pwb;                                                     \
                {                                                                   \
                    float p0 = EXP2(c[0]),  p1 = EXP2(c[1]);                        \
                    float p2 = EXP2(c[2]),  p3 = EXP2(c[3]);                        \
                    ls0 += p0 + p1; ls1 += p2 + p3;                                 \
                    asm("v_cvt_pk_bf16_f32 %0, %1, %2" : "=v"(pwa.x) : "v"(p0), "v"(p1)); \
                    asm("v_cvt_pk_bf16_f32 %0, %1, %2" : "=v"(pwa.y) : "v"(p2), "v"(p3)); \
                    p0 = EXP2(c[4]);  p1 = EXP2(c[5]);                              \
                    p2 = EXP2(c[6]);  p3 = EXP2(c[7]);                              \
                    ls0 += p0 + p1; ls1 += p2 + p3;                                 \
                    asm("v_cvt_pk_bf16_f32 %0, %1, %2" : "=v"(pwa.z) : "v"(p0), "v"(p1)); \
                    asm("v_cvt_pk_bf16_f32 %0, %1, %2" : "=v"(pwa.w) : "v"(p2), "v"(p3)); \
                    p0 = EXP2(c[8]);  p1 = EXP2(c[9]);                              \
                    p2 = EXP2(c[10]); p3 = EXP2(c[11]);                             \
                    ls0 += p0 + p1; ls1 += p2 + p3;                                 \
                    asm("v_cvt_pk_bf16_f32 %0, %1, %2" : "=v"(pwb.x) : "v"(p0), "v"(p1)); \
                    asm("v_cvt_pk_bf16_f32 %0, %1, %2" : "=v"(pwb.y) : "v"(p2), "v"(p3)); \
                    p0 = EXP2(c[12]); p1 = EXP2(c[13]);                             \
                    p2 = EXP2(c[14]); p3 = EXP2(c[15]);                             \
                    ls0 += p0 + p1; ls1 += p2 + p3;                                 \
                    asm("v_cvt_pk_bf16_f32 %0, %1, %2" : "=v"(pwb.z) : "v"(p0), "v"(p1)); \
                    asm("v_cvt_pk_bf16_f32 %0, %1, %2" : "=v"(pwb.w) : "v"(p2), "v"(p3)); \
                }                                                                   \
                asm("v_permlane32_swap_b32 %0, %1" : "+v"(pwa.x), "+v"(pwa.z));     \
                asm("v_permlane32_swap_b32 %0, %1" : "+v"(pwa.y), "+v"(pwa.w));     \
                asm("v_permlane32_swap_b32 %0, %1" : "+v"(pwb.x), "+v"(pwb.z));     \
                asm("v_permlane32_swap_b32 %0, %1" : "+v"(pwb.y), "+v"(pwb.w));     \
                __builtin_amdgcn_s_setprio(1);                                      \
                {                                                                   \
                    int vg0 = tc * 4 + hi;                                          \
                    bf16x8 pa = as_bf16x8(pwa);                                     \
                    bf16x8 v0 = as_bf16x8(sV[BUF][ l5       * 8 + (vg0 ^ (l5 & 7))]); \
                    Oa0 = __builtin_amdgcn_mfma_f32_32x32x16_bf16(pa, v0, Oa0, 0, 0, 0); \
                    bf16x8 v1 = as_bf16x8(sV[BUF][(32 + l5) * 8 + (vg0 ^ (l5 & 7))]); \
                    Oa1 = __builtin_amdgcn_mfma_f32_32x32x16_bf16(pa, v1, Oa1, 0, 0, 0); \
                    int vg1 = tc * 4 + 2 + hi;                                      \
                    bf16x8 pb = as_bf16x8(pwb);                                     \
                    bf16x8 v2 = as_bf16x8(sV[BUF][ l5       * 8 + (vg1 ^ (l5 & 7))]); \
                    Oa0 = __builtin_amdgcn_mfma_f32_32x32x16_bf16(pb, v2, Oa0, 0, 0, 0); \
                    bf16x8 v3 = as_bf16x8(sV[BUF][(32 + l5) * 8 + (vg1 ^ (l5 & 7))]); \
                    Oa1 = __builtin_amdgcn_mfma_f32_32x32x16_bf16(pb, v3, Oa1, 0, 0, 0); \
                }                                                                   \
                __builtin_amdgcn_s_setprio(0);                                      \
            }                                                                       \
        } while (0)

    STAGE(0, 0);

    for (int tt = 0; tt < LSEQ / 64; tt += 2) {
        STAGE(tt + 1, 1);
        asm volatile("s_waitcnt vmcnt(4)" ::: "memory");
        __builtin_amdgcn_s_barrier();
        COMPUTE(0);
        __builtin_amdgcn_s_barrier();

        if (tt + 2 < LSEQ / 64) {
            STAGE(tt + 2, 0);
            asm volatile("s_waitcnt vmcnt(4)" ::: "memory");
        } else {
            asm volatile("s_waitcnt vmcnt(0)" ::: "memory");
        }
        __builtin_amdgcn_s_barrier();
        COMPUTE(1);
        __builtin_amdgcn_s_barrier();
    }
    #undef STAGE
    #undef COMPUTE

    float lsum = ls0 + ls1;
    lsum += __shfl_xor(lsum, 32);
    float inv = 1.0f / lsum;
    float* sLf = (float*)&sK[0][0];
    if (hi == 0) sLf[w * 32 + l5] = inv;
    __syncthreads();

    unsigned short* hB = AOh + hoff;
    unsigned short* lB = AOl + hoff;
    #pragma unroll
    for (int r = 0; r < 16; ++r) {
        int qr = (r & 3) + 8 * (r >> 2) + 4 * hi;
        float invq = sLf[w * 32 + qr];
        size_t row = (size_t)(q0 + w * 32 + qr) * HD;
        float o0 = Oa0[r] * invq;
        float o1 = Oa1[r] * invq;
        unsigned short h0 = bf16r(o0), h1 = bf16r(o1);
        hB[row +      l5] = h0;
        hB[row + 32 + l5] = h1;
        lB[row +      l5] = bf16r(o0 - bfh2f(h0));
        lB[row + 32 + l5] = bf16r(o1 - bfh2f(h1));
    }
}

// ---------------------------------------------------------------------------
// Kernel 3: output projection, split-bf16 MFMA GEMM.
// R17: K-chunk 32 -> 64 (one full head per chunk).  Three implementations
// (R8/R14/R16) all landed at 83-88us with MfmaUtil ~24% — conflicts, VALU,
// and occupancy were each eliminated with zero effect.  The shared trait is
// the sync cadence: 32 chunks x {12 MFMA (~100cy) between barriers} cannot
// cover ~300-500cy load latency.  Now: 16 chunks x 24 MFMA per barrier pair
// (2x compute per sync, half the barriers).  B in LDS sB[2][64][16] (32KB;
// granule swizzle: low 3 bits ^ SW(row), bit3 = hi/lo select; read rows
// thread-fixed -> swizzle free).  A in registers, 8 x bf16x8 per buffer,
// ping-pong with fully-unrolled compile-time indices (rule #20).
// vmcnt(12) = {4 gload_lds + 8 A-loads} just issued.  launch_bounds(256,3):
// est VGPR ~130 < 170 cap (R15 spill lesson).  Guard: WRITE_SIZE 32.8MB.
// ---------------------------------------------------------------------------
__global__ __launch_bounds__(256, 3) void outproj_kernel(
    const unsigned short* __restrict__ AOh, const unsigned short* __restrict__ AOl,
    const unsigned short* __restrict__ Woh, const unsigned short* __restrict__ Wol,
    const float* __restrict__ bo, float* __restrict__ out)
{
    __shared__ uint4 sB[2][1024];   // [buf][e row 0..63][16 granules] 16KB each

    const int t = threadIdx.x;
    const int lane = t & 63, w = t >> 6;
    const int l5 = lane & 31, hi = lane >> 5;

    // T1 remap: l -> (xcd, u); m-tile = xcd*8 + (u&7), e-tile = u>>3.
    const int bl  = blockIdx.x + blockIdx.y * 64;
    const int xcd = bl & 7, u = bl >> 3;
    const int m0  = (xcd * 8 + (u & 7)) * 128;
    const int e0  = (u >> 3) * 64;
    const int n   = m0 >> 11, l0 = m0 & 2047;

    #define SW(r) (((r) ^ ((r) >> 3)) & 7)

    // stage chunk C (= head hh): slot s = row*16 + q; q&8 selects h/l,
    // source granule = (q&7) ^ SW(row).  4 slots/thread.
    #define BSTAGE(C, BUF)                                                            \
        do {                                                                          \
            const uint4* gBh_ = (const uint4*)(Woh) + (size_t)e0 * 128 + (C) * 8;     \
            const uint4* gBl_ = (const uint4*)(Wol) + (size_t)e0 * 128 + (C) * 8;     \
            _Pragma("unroll")                                                         \
            for (int i_ = 0; i_ < 4; ++i_) {                                          \
                int s_ = t + 256 * i_;                                                \
                int row_ = s_ >> 4, q_ = s_ & 15;                                     \
                int sg_ = (q_ & 7) ^ SW(row_);                                        \
                const uint4* src_ = ((q_ & 8) ? gBl_ : gBh_) +                        \
                    (size_t)row_ * 128 + sg_;                                         \
                gload_lds16(src_, &sB[BUF][s_]);                                      \
            }                                                                         \
        } while (0)

    const int amr = w * 32 + l5;                 // this thread's A row (fixed)
    const size_t aRow = ((size_t)n * HEADS) * LSEQ * 8 + (size_t)(l0 + amr) * 8;
    const uint4* pAh = (const uint4*)AOh + aRow;
    const uint4* pAl = (const uint4*)AOl + aRow;
    // chunk C = head: row offset C*LSEQ*8; granules 2*ks+hi, ks=0..3, h then l.
    #define ALOAD(C, AH, AL)                                                          \
        do {                                                                          \
            size_t off_ = (size_t)(C) * (LSEQ * 8) + hi;                              \
            _Pragma("unroll")                                                         \
            for (int ks_ = 0; ks_ < 4; ++ks_) {                                       \
                AH[ks_] = as_bf16x8(pAh[off_ + 2 * ks_]);                             \
                AL[ks_] = as_bf16x8(pAl[off_ + 2 * ks_]);                             \
            }                                                                         \
        } while (0)

    const int swb0 = SW(l5);
    const int swb1 = SW(32 + l5);

    #define OCOMPUTE(BUF, AH, AL)                                                     \
        do {                                                                          \
            __builtin_amdgcn_s_setprio(1);                                            \
            _Pragma("unroll")                                                         \
            for (int ks = 0; ks < 4; ++ks) {                                          \
                int gx = ks * 2 + hi;                                                 \
                bf16x8 ah = AH[ks];                                                   \
                bf16x8 al = AL[ks];                                                   \
                bf16x8 bh0 = as_bf16x8(sB[BUF][ l5       * 16 +     (gx ^ swb0)]);    \
                bf16x8 bh1 = as_bf16x8(sB[BUF][(32 + l5) * 16 +     (gx ^ swb1)]);    \
                bf16x8 bl0 = as_bf16x8(sB[BUF][ l5       * 16 + 8 + (gx ^ swb0)]);    \
                bf16x8 bl1 = as_bf16x8(sB[BUF][(32 + l5) * 16 + 8 + (gx ^ swb1)]);    \
                acc0 = __builtin_amdgcn_mfma_f32_32x32x16_bf16(ah, bh0, acc0, 0, 0, 0); \
                acc1 = __builtin_amdgcn_mfma_f32_32x32x16_bf16(ah, bh1, acc1, 0, 0, 0); \
                acc0 = __builtin_amdgcn_mfma_f32_32x32x16_bf16(ah, bl0, acc0, 0, 0, 0); \
                acc1 = __builtin_amdgcn_mfma_f32_32x32x16_bf16(ah, bl1, acc1, 0, 0, 0); \
                acc0 = __builtin_amdgcn_mfma_f32_32x32x16_bf16(al, bh0, acc0, 0, 0, 0); \
                acc1 = __builtin_amdgcn_mfma_f32_32x32x16_bf16(al, bh1, acc1, 0, 0, 0); \
            }                                                                         \
            __builtin_amdgcn_s_setprio(0);                                            \
        } while (0)

    f32x16 acc0, acc1;
    #pragma unroll
    for (int i = 0; i < 16; ++i) { acc0[i] = 0.f; acc1[i] = 0.f; }

    bf16x8 eAH[4], eAL[4];          // even-chunk A frags
    bf16x8 oAH[4], oAL[4];          // odd-chunk A frags

    BSTAGE(0, 0);
    ALOAD(0, eAH, eAL);

    #pragma unroll 1
    for (int c = 0; c < 16; c += 2) {
        BSTAGE(c + 1, 1);
        ALOAD(c + 1, oAH, oAL);
        asm volatile("s_waitcnt vmcnt(12)" ::: "memory");
        __builtin_amdgcn_s_barrier();
        OCOMPUTE(0, eAH, eAL);
        __builtin_amdgcn_s_barrier();

        if (c + 2 < 16) {
            BSTAGE(c + 2, 0);
            ALOAD(c + 2, eAH, eAL);
            asm volatile("s_waitcnt vmcnt(12)" ::: "memory");
        } else {
            asm volatile("s_waitcnt vmcnt(0)" ::: "memory");
        }
        __builtin_amdgcn_s_barrier();
        OCOMPUTE(1, oAH, oAL);
        __builtin_amdgcn_s_barrier();
    }
    #undef BSTAGE
    #undef ALOAD
    #undef OCOMPUTE
    #undef SW

    float b0 = bo[e0 + l5];
    float b1 = bo[e0 + 32 + l5];
    #pragma unroll
    for (int r = 0; r < 16; ++r) {
        int row = m0 + w * 32 + (r & 3) + 8 * (r >> 2) + 4 * hi;
        float* o = out + (size_t)row * EMBED + e0;
        o[l5]      = acc0[r] + b0;
        o[32 + l5] = acc1[r] + b1;
    }
}

// ---------------------------------------------------------------------------
extern "C" void kernel_launch(void* const* d_in, const int* in_sizes, int n_in,
                              void* d_out, int out_size, void* d_ws, size_t ws_size,
                              hipStream_t stream)
{
    const float* values  = (const float*)d_in[0];
    const float* keys    = (const float*)d_in[1];
    const float* queries = (const float*)d_in[2];
    const float* Wv      = (const float*)d_in[3];
    const float* Wk      = (const float*)d_in[4];
    const float* Wq      = (const float*)d_in[5];
    const float* Wo      = (const float*)d_in[6];
    const float* bo      = (const float*)d_in[7];
    float* out = (float*)d_out;

    const size_t bufElems = (size_t)NB * HEADS * LSEQ * HD;   // 8,388,608
    unsigned short* Qp  = (unsigned short*)d_ws;
    unsigned short* Kp  = Qp  + bufElems;
    unsigned short* Vt  = Kp  + bufElems;
    unsigned short* AOh = Vt  + bufElems;
    unsigned short* AOl = AOh + bufElems;
    unsigned short* Woh = AOl + bufElems;
    unsigned short* Wol = Woh + (size_t)EMBED * EMBED;

    proj_kernel<<<dim3(NB * 16, HEADS, 4), 256, 0, stream>>>(
        values, keys, queries, Wv, Wk, Wq, Wo, Vt, Kp, Qp, Woh, Wol);
    attn_kernel<<<dim3(LSEQ / 128, HEADS, NB), 256, 0, stream>>>(Qp, Kp, Vt, AOh, AOl);
    outproj_kernel<<<dim3(NB * LSEQ / 128, EMBED / 64), 256, 0, stream>>>(AOh, AOl, Woh, Wol, bo, out);
}

// Round 14
// 312.498 us; speedup vs baseline: 1.0548x; 1.0417x over previous
//
#include <hip/hip_runtime.h>
#include <math.h>

#define EMBED 1024
#define HEADS 16
#define HD    64
#define NB    4
#define LSEQ  2048

typedef __attribute__((ext_vector_type(8))) short bf16x8;
typedef __attribute__((ext_vector_type(16))) float f32x16;

typedef __attribute__((address_space(1))) void as1_void;
typedef __attribute__((address_space(3))) void as3_void;

#if __has_builtin(__builtin_amdgcn_exp2f)
#define EXP2(x) __builtin_amdgcn_exp2f(x)
#else
#define EXP2(x) exp2f(x)
#endif

__device__ __forceinline__ void gload_lds16(const void* g, void* l) {
    __builtin_amdgcn_global_load_lds((const as1_void*)g, (as3_void*)l, 16, 0, 0);
}

__device__ inline bf16x8 as_bf16x8(uint4 u) {
    union { uint4 u; bf16x8 b; } c; c.u = u; return c.b;
}
// round-to-nearest-even fp32 -> bf16 (raw ushort); finite inputs only
__device__ inline unsigned short bf16r(float x) {
    unsigned u = __float_as_uint(x);
    u += 0x7fffu + ((u >> 16) & 1u);
    return (unsigned short)(u >> 16);
}
__device__ inline float bfh2f(unsigned short h) {
    return __uint_as_float(((unsigned)h) << 16);
}
// split two floats into packed hi/lo bf16 words
__device__ inline void split2(float x, float y, unsigned& hw, unsigned& lw) {
    unsigned short hx = bf16r(x), hy = bf16r(y);
    unsigned short lx = bf16r(x - bfh2f(hx)), ly = bf16r(y - bfh2f(hy));
    hw = (unsigned)hx | ((unsigned)hy << 16);
    lw = (unsigned)lx | ((unsigned)ly << 16);
}

// ---------------------------------------------------------------------------
// Kernel 1: QKV projections as split-bf16 MFMA GEMM.
// R18 (T14 on the z-split form): each GEMM block owns TWO adjacent 128-token
// tiles.  W is loaded+split once; tile-1's 8 X float4 loads are issued
// before tile-0's MFMA+epilogue and land under ~1100cy of compute/stores,
// instead of each block exposing its full X-load latency serially.
// Per-block VALU drops 25% (W split shared).  Grid x halves; the wsplit
// z==3 slice processes 2 float4 per thread.  VGPR est ~110-130 < 170 cap.
// ---------------------------------------------------------------------------
__global__ __launch_bounds__(256, 3) void proj_kernel(
    const float* __restrict__ Xv, const float* __restrict__ Xk, const float* __restrict__ Xq,
    const float* __restrict__ Wv, const float* __restrict__ Wk, const float* __restrict__ Wq,
    const float* __restrict__ Wo,
    unsigned short* __restrict__ Vt, unsigned short* __restrict__ Kp, unsigned short* __restrict__ Qp,
    unsigned short* __restrict__ Woh, unsigned short* __restrict__ Wol)
{
    __shared__ uint4 sXh[128 * 8];   // [token][granule of 8 dims]  16KB
    __shared__ uint4 sXl[128 * 8];   // 16KB
    __shared__ uint4 sWh[64 * 8];    // [e][granule of 8 dims]       8KB
    __shared__ uint4 sWl[64 * 8];    //                              8KB

    const int t = threadIdx.x;

    // ---- z == 3: Wo hi/lo split (2 float4 per thread; 512 blocks) ----
    if (blockIdx.z == 3) {
        int w_id = blockIdx.x + blockIdx.y * 32;          // 0..511
        int i0 = w_id * 256 + t;
        #pragma unroll
        for (int rep = 0; rep < 2; ++rep) {
            int i = i0 + rep * 131072;
            float4 v = ((const float4*)Wo)[i];
            ushort4 h4, l4;
            h4.x = bf16r(v.x); l4.x = bf16r(v.x - bfh2f(h4.x));
            h4.y = bf16r(v.y); l4.y = bf16r(v.y - bfh2f(h4.y));
            h4.z = bf16r(v.z); l4.z = bf16r(v.z - bfh2f(h4.z));
            h4.w = bf16r(v.w); l4.w = bf16r(v.w - bfh2f(h4.w));
            ((ushort4*)Woh)[i] = h4;
            ((ushort4*)Wol)[i] = l4;
        }
        return;
    }

    const int lane = t & 63, w = t >> 6;
    const int l5 = lane & 31, hi = lane >> 5;
    const int h  = blockIdx.y;
    const int n  = blockIdx.x >> 3;
    const int l0 = (blockIdx.x & 7) * 256;    // two tiles: l0, l0+128
    const int p  = blockIdx.z;

    const float QSC = 1.44269504088896341f / 32.0f;
    const float* Xp = (p == 0) ? Xv : (p == 1) ? Xk : Xq;
    const float* Wp = (p == 0) ? Wv : (p == 1) ? Wk : Wq;

    const int frow = t >> 4;        // staging: row group 0..15
    const int fcol = t & 15;        // float4 index within 64-dim row

    // ---- issue W loads first, then X0 (so W's split waits only on W) ----
    const float* wb0 = Wp + (size_t)t * 8;
    const float* wb1 = Wp + (size_t)(t + 256) * 8;
    float4 wr0 = *(const float4*)(wb0);
    float4 wr1 = *(const float4*)(wb0 + 4);
    float4 wr2 = *(const float4*)(wb1);
    float4 wr3 = *(const float4*)(wb1 + 4);

    const float* xbase = Xp + ((size_t)(n * LSEQ + l0 + frow)) * EMBED + h * HD + fcol * 4;
    float4 xr[8];
    #pragma unroll
    for (int i = 0; i < 8; ++i) xr[i] = *(const float4*)(xbase + (size_t)i * 16 * EMBED);

    // ---- split + store W (once for both tiles) ----
    {
        uint4 hq, lq;
        split2(wr0.x, wr0.y, hq.x, lq.x);
        split2(wr0.z, wr0.w, hq.y, lq.y);
        split2(wr1.x, wr1.y, hq.z, lq.z);
        split2(wr1.z, wr1.w, hq.w, lq.w);
        int e = t >> 3, g = t & 7;
        sWh[e * 8 + (g ^ (e & 7))] = hq;
        sWl[e * 8 + (g ^ (e & 7))] = lq;
        split2(wr2.x, wr2.y, hq.x, lq.x);
        split2(wr2.z, wr2.w, hq.y, lq.y);
        split2(wr3.x, wr3.y, hq.z, lq.z);
        split2(wr3.z, wr3.w, hq.w, lq.w);
        int u = t + 256;
        e = u >> 3; g = u & 7;
        sWh[e * 8 + (g ^ (e & 7))] = hq;
        sWl[e * 8 + (g ^ (e & 7))] = lq;
    }

    // split + store an X tile held in xr[]
    #define STOREX()                                                            \
        do {                                                                    \
            unsigned short* dh = (unsigned short*)sXh;                          \
            unsigned short* dl = (unsigned short*)sXl;                          \
            _Pragma("unroll")                                                   \
            for (int i = 0; i < 8; ++i) {                                       \
                int row = frow + i * 16;                                        \
                int gg = fcol >> 1, s8 = (fcol & 1) * 4;                        \
                int idx = row * 64 + ((gg ^ (row & 7)) * 8) + s8;               \
                uint2 hv, lv;                                                   \
                split2(xr[i].x, xr[i].y, hv.x, lv.x);                           \
                split2(xr[i].z, xr[i].w, hv.y, lv.y);                           \
                *(uint2*)(dh + idx) = hv;                                       \
                *(uint2*)(dl + idx) = lv;                                       \
            }                                                                   \
        } while (0)

    // MFMA over the staged tile + epilogue at token base L0T
    #define PC_TILE(L0T)                                                        \
        do {                                                                    \
            f32x16 acc0, acc1;                                                  \
            _Pragma("unroll")                                                   \
            for (int i = 0; i < 16; ++i) { acc0[i] = 0.f; acc1[i] = 0.f; }      \
            const int xrow = w * 32 + l5;                                       \
            const int w0r = l5, w1r = 32 + l5;                                  \
            _Pragma("unroll")                                                   \
            for (int kc = 0; kc < 4; ++kc) {                                    \
                int gsel = kc * 2 + hi;                                         \
                bf16x8 xh = as_bf16x8(sXh[xrow * 8 + (gsel ^ (xrow & 7))]);     \
                bf16x8 xl = as_bf16x8(sXl[xrow * 8 + (gsel ^ (xrow & 7))]);     \
                bf16x8 wh0 = as_bf16x8(sWh[w0r * 8 + (gsel ^ (w0r & 7))]);      \
                bf16x8 wl0 = as_bf16x8(sWl[w0r * 8 + (gsel ^ (w0r & 7))]);      \
                bf16x8 wh1 = as_bf16x8(sWh[w1r * 8 + (gsel ^ (w1r & 7))]);      \
                bf16x8 wl1 = as_bf16x8(sWl[w1r * 8 + (gsel ^ (w1r & 7))]);      \
                if (p == 0) {                                                   \
                    acc0 = __builtin_amdgcn_mfma_f32_32x32x16_bf16(wh0, xh, acc0, 0, 0, 0); \
                    acc0 = __builtin_amdgcn_mfma_f32_32x32x16_bf16(wh0, xl, acc0, 0, 0, 0); \
                    acc0 = __builtin_amdgcn_mfma_f32_32x32x16_bf16(wl0, xh, acc0, 0, 0, 0); \
                    acc1 = __builtin_amdgcn_mfma_f32_32x32x16_bf16(wh1, xh, acc1, 0, 0, 0); \
                    acc1 = __builtin_amdgcn_mfma_f32_32x32x16_bf16(wh1, xl, acc1, 0, 0, 0); \
                    acc1 = __builtin_amdgcn_mfma_f32_32x32x16_bf16(wl1, xh, acc1, 0, 0, 0); \
                } else {                                                        \
                    acc0 = __builtin_amdgcn_mfma_f32_32x32x16_bf16(xh, wh0, acc0, 0, 0, 0); \
                    acc0 = __builtin_amdgcn_mfma_f32_32x32x16_bf16(xh, wl0, acc0, 0, 0, 0); \
                    acc0 = __builtin_amdgcn_mfma_f32_32x32x16_bf16(xl, wh0, acc0, 0, 0, 0); \
                    acc1 = __builtin_amdgcn_mfma_f32_32x32x16_bf16(xh, wh1, acc1, 0, 0, 0); \
                    acc1 = __builtin_amdgcn_mfma_f32_32x32x16_bf16(xh, wl1, acc1, 0, 0, 0); \
                    acc1 = __builtin_amdgcn_mfma_f32_32x32x16_bf16(xl, wh1, acc1, 0, 0, 0); \
                }                                                               \
            }                                                                   \
            if (p == 0) {                                                       \
                unsigned short* vb = Vt + (((size_t)(n * HEADS + h)) * HD) * LSEQ \
                                     + (L0T) + w * 32 + l5;                     \
                _Pragma("unroll")                                               \
                for (int r = 0; r < 16; ++r) {                                  \
                    int er = (r & 3) + 8 * (r >> 2) + 4 * hi;                   \
                    vb[(size_t)er * LSEQ]        = bf16r(acc0[r]);              \
                    vb[(size_t)(32 + er) * LSEQ] = bf16r(acc1[r]);              \
                }                                                               \
            } else {                                                            \
                unsigned short* dst = (p == 1) ? Kp : Qp;                       \
                float sc = (p == 2) ? QSC : 1.0f;                               \
                unsigned short* db = dst + (((size_t)(n * HEADS + h)) * LSEQ    \
                                     + (L0T) + w * 32) * HD;                    \
                _Pragma("unroll")                                               \
                for (int r = 0; r < 16; ++r) {                                  \
                    int tok = (r & 3) + 8 * (r >> 2) + 4 * hi;                  \
                    db[(size_t)tok * HD + l5]      = bf16r(acc0[r] * sc);       \
                    db[(size_t)tok * HD + 32 + l5] = bf16r(acc1[r] * sc);       \
                }                                                               \
            }                                                                   \
        } while (0)

    // ---- tile 0 staged; issue tile-1 loads (fly over MFMA0 + epilogue0) ----
    STOREX();
    {
        const float* xbase1 = xbase + (size_t)128 * EMBED;
        #pragma unroll
        for (int i = 0; i < 8; ++i) xr[i] = *(const float4*)(xbase1 + (size_t)i * 16 * EMBED);
    }
    __syncthreads();
    PC_TILE(l0);
    __syncthreads();                 // all waves done reading sX tile 0
    STOREX();                        // split+store tile 1 (loads have landed)
    __syncthreads();
    PC_TILE(l0 + 128);

    #undef STOREX
    #undef PC_TILE
}

// ---------------------------------------------------------------------------
// Kernel 2: MFMA flash attention (R13 form, unchanged — 84us known-good).
// ---------------------------------------------------------------------------
__global__ __launch_bounds__(256, 4) void attn_kernel(
    const unsigned short* __restrict__ Qp, const unsigned short* __restrict__ Kp,
    const unsigned short* __restrict__ Vt,
    unsigned short* __restrict__ AOh, unsigned short* __restrict__ AOl)
{
    __shared__ uint4 sK[2][64 * 8];  // [buf][key][granule]  8KB each
    __shared__ uint4 sV[2][64 * 8];  // [buf][d][key-granule] 8KB each

    const int t = threadIdx.x;
    const int lane = t & 63, w = t >> 6;
    const int l5 = lane & 31, hi = lane >> 5;

    // T1 remap: b -> (xcd, u); group = xcd*8 + (u>>4) owns q-tiles u&15.
    const int b   = blockIdx.x + blockIdx.y * 16 + blockIdx.z * 256;
    const int xcd = b & 7, u = b >> 3;
    const int grp = xcd * 8 + (u >> 4);
    const int n   = grp >> 4, h = grp & 15;
    const int q0  = (u & 15) * 128;

    const size_t hoff = ((size_t)n * HEADS + h) * (size_t)(LSEQ * HD);
    const unsigned short* Kh = Kp + hoff;
    const unsigned short* Vh = Vt + hoff;

    bf16x8 qf[4];
    {
        const uint4* qg = (const uint4*)(Qp + hoff + (size_t)(q0 + w * 32 + l5) * HD);
        #pragma unroll
        for (int kc = 0; kc < 4; ++kc) qf[kc] = as_bf16x8(qg[kc * 2 + hi]);
    }

    f32x16 z16;
    #pragma unroll
    for (int i = 0; i < 16; ++i) z16[i] = 0.f;
    f32x16 Oa0 = z16, Oa1 = z16;
    float ls0 = 0.f, ls1 = 0.f;

    const int r0 = t >> 3;                       // key-row / d-row 0..31
    const int g0 = (t & 7) ^ (r0 & 7);           // swizzled granule
    const uint4* gK = (const uint4*)Kh;
    const uint4* gV = (const uint4*)Vh;          // V^T: 256 uint4 per d-row

    #define STAGE(TILE, BUF)                                                        \
        do {                                                                        \
            int kb_ = (TILE) * 64;                                                  \
            gload_lds16(gK + (size_t)(kb_ + r0) * 8 + g0,        &sK[BUF][t]);      \
            gload_lds16(gK + (size_t)(kb_ + r0 + 32) * 8 + g0,   &sK[BUF][t + 256]);\
            gload_lds16(gV + (size_t)r0 * 256 + (kb_ >> 3) + g0, &sV[BUF][t]);      \
            gload_lds16(gV + (size_t)(r0 + 32) * 256 + (kb_ >> 3) + g0,             \
                        &sV[BUF][t + 256]);                                         \
        } while (0)

    #define COMPUTE(BUF)                                                            \
        do {                                                                        \
            _Pragma("unroll")                                                       \
            for (int tc = 0; tc < 2; ++tc) {                                        \
                int key = tc * 32 + l5;                                             \
                __builtin_amdgcn_s_setprio(1);                                      \
                bf16x8 kf0 = as_bf16x8(sK[BUF][key * 8 + (hi ^ (l5 & 7))]);         \
                f32x16 c = __builtin_amdgcn_mfma_f32_32x32x16_bf16(kf0, qf[0], z16, 0, 0, 0); \
                _Pragma("unroll")                                                   \
                for (int kc = 1; kc < 4; ++kc) {                                    \
                    bf16x8 kf = as_bf16x8(sK[BUF][key * 8 + ((kc * 2 + hi) ^ (l5 & 7))]); \
                    c = __builtin_amdgcn_mfma_f32_32x32x16_bf16(kf, qf[kc], c, 0, 0, 0);  \
                }                                                                   \
                __builtin_amdgcn_s_setprio(0);                                      \
                uint4 pwa, pwb;                                                     \
                {                                                                   \
                    float p0 = EXP2(c[0]),  p1 = EXP2(c[1]);                        \
                    float p2 = EXP2(c[2]),  p3 = EXP2(c[3]);                        \
                    ls0 += p0 + p1; ls1 += p2 + p3;                                 \
                    asm("v_cvt_pk_bf16_f32 %0, %1, %2" : "=v"(pwa.x) : "v"(p0), "v"(p1)); \
                    asm("v_cvt_pk_bf16_f32 %0, %1, %2" : "=v"(pwa.y) : "v"(p2), "v"(p3)); \
                    p0 = EXP2(c[4]);  p1 = EXP2(c[5]);                              \
                    p2 = EXP2(c[6]);  p3 = EXP2(c[7]);                              \
                    ls0 += p0 + p1; ls1 += p2 + p3;                                 \
                    asm("v_cvt_pk_bf16_f32 %0, %1, %2" : "=v"(pwa.z) : "v"(p0), "v"(p1)); \
                    asm("v_cvt_pk_bf16_f32 %0, %1, %2" : "=v"(pwa.w) : "v"(p2), "v"(p3)); \
                    p0 = EXP2(c[8]);  p1 = EXP2(c[9]);                              \
                    p2 = EXP2(c[10]); p3 = EXP2(c[11]);                             \
                    ls0 += p0 + p1; ls1 += p2 + p3;                                 \
                    asm("v_cvt_pk_bf16_f32 %0, %1, %2" : "=v"(pwb.x) : "v"(p0), "v"(p1)); \
                    asm("v_cvt_pk_bf16_f32 %0, %1, %2" : "=v"(pwb.y) : "v"(p2), "v"(p3)); \
                    p0 = EXP2(c[12]); p1 = EXP2(c[13]);                             \
                    p2 = EXP2(c[14]); p3 = EXP2(c[15]);                             \
                    ls0 += p0 + p1; ls1 += p2 + p3;                                 \
                    asm("v_cvt_pk_bf16_f32 %0, %1, %2" : "=v"(pwb.z) : "v"(p0), "v"(p1)); \
                    asm("v_cvt_pk_bf16_f32 %0, %1, %2" : "=v"(pwb.w) : "v"(p2), "v"(p3)); \
                }                                                                   \
                asm("v_permlane32_swap_b32 %0, %1" : "+v"(pwa.x), "+v"(pwa.z));     \
                asm("v_permlane32_swap_b32 %0, %1" : "+v"(pwa.y), "+v"(pwa.w));     \
                asm("v_permlane32_swap_b32 %0, %1" : "+v"(pwb.x), "+v"(pwb.z));     \
                asm("v_permlane32_swap_b32 %0, %1" : "+v"(pwb.y), "+v"(pwb.w));     \
                __builtin_amdgcn_s_setprio(1);                                      \
                {                                                                   \
                    int vg0 = tc * 4 + hi;                                          \
                    bf16x8 pa = as_bf16x8(pwa);                                     \
                    bf16x8 v0 = as_bf16x8(sV[BUF][ l5       * 8 + (vg0 ^ (l5 & 7))]); \
                    Oa0 = __builtin_amdgcn_mfma_f32_32x32x16_bf16(pa, v0, Oa0, 0, 0, 0); \
                    bf16x8 v1 = as_bf16x8(sV[BUF][(32 + l5) * 8 + (vg0 ^ (l5 & 7))]); \
                    Oa1 = __builtin_amdgcn_mfma_f32_32x32x16_bf16(pa, v1, Oa1, 0, 0, 0); \
                    int vg1 = tc * 4 + 2 + hi;                                      \
                    bf16x8 pb = as_bf16x8(pwb);                                     \
                    bf16x8 v2 = as_bf16x8(sV[BUF][ l5       * 8 + (vg1 ^ (l5 & 7))]); \
                    Oa0 = __builtin_amdgcn_mfma_f32_32x32x16_bf16(pb, v2, Oa0, 0, 0, 0); \
                    bf16x8 v3 = as_bf16x8(sV[BUF][(32 + l5) * 8 + (vg1 ^ (l5 & 7))]); \
                    Oa1 = __builtin_amdgcn_mfma_f32_32x32x16_bf16(pb, v3, Oa1, 0, 0, 0); \
                }                                                                   \
                __builtin_amdgcn_s_setprio(0);                                      \
            }                                                                       \
        } while (0)

    STAGE(0, 0);

    for (int tt = 0; tt < LSEQ / 64; tt += 2) {
        STAGE(tt + 1, 1);
        asm volatile("s_waitcnt vmcnt(4)" ::: "memory");
        __builtin_amdgcn_s_barrier();
        COMPUTE(0);
        __builtin_amdgcn_s_barrier();

        if (tt + 2 < LSEQ / 64) {
            STAGE(tt + 2, 0);
            asm volatile("s_waitcnt vmcnt(4)" ::: "memory");
        } else {
            asm volatile("s_waitcnt vmcnt(0)" ::: "memory");
        }
        __builtin_amdgcn_s_barrier();
        COMPUTE(1);
        __builtin_amdgcn_s_barrier();
    }
    #undef STAGE
    #undef COMPUTE

    float lsum = ls0 + ls1;
    lsum += __shfl_xor(lsum, 32);
    float inv = 1.0f / lsum;
    float* sLf = (float*)&sK[0][0];
    if (hi == 0) sLf[w * 32 + l5] = inv;
    __syncthreads();

    unsigned short* hB = AOh + hoff;
    unsigned short* lB = AOl + hoff;
    #pragma unroll
    for (int r = 0; r < 16; ++r) {
        int qr = (r & 3) + 8 * (r >> 2) + 4 * hi;
        float invq = sLf[w * 32 + qr];
        size_t row = (size_t)(q0 + w * 32 + qr) * HD;
        float o0 = Oa0[r] * invq;
        float o1 = Oa1[r] * invq;
        unsigned short h0 = bf16r(o0), h1 = bf16r(o1);
        hB[row +      l5] = h0;
        hB[row + 32 + l5] = h1;
        lB[row +      l5] = bf16r(o0 - bfh2f(h0));
        lB[row + 32 + l5] = bf16r(o1 - bfh2f(h1));
    }
}

// ---------------------------------------------------------------------------
// Kernel 3: output projection, split-bf16 MFMA GEMM (exact R14 revert — the
// best-measured form: below the 83.3-84.2 top-5 cutoffs in R9-R11.  R16's
// A-in-reg and R17's K-chunk-64 were both null-to-negative).
// ---------------------------------------------------------------------------
__global__ __launch_bounds__(256, 3) void outproj_kernel(
    const unsigned short* __restrict__ AOh, const unsigned short* __restrict__ AOl,
    const unsigned short* __restrict__ Woh, const unsigned short* __restrict__ Wol,
    const float* __restrict__ bo, float* __restrict__ out)
{
    __shared__ uint4 sA[2][1024];   // [buf][token row 0..127][8 granules] 16KB each
    __shared__ uint4 sB[2][512];    // [buf][e row 0..63][8 granules]       8KB each

    const int t = threadIdx.x;
    const int lane = t & 63, w = t >> 6;
    const int l5 = lane & 31, hi = lane >> 5;

    // T1 remap: l -> (xcd, u); m-tile = xcd*8 + (u&7), e-tile = u>>3.
    const int bl  = blockIdx.x + blockIdx.y * 64;
    const int xcd = bl & 7, u = bl >> 3;
    const int m0  = (xcd * 8 + (u & 7)) * 128;
    const int e0  = (u >> 3) * 64;
    const int n   = m0 >> 11, l0 = m0 & 2047;

    #define SW(r) (((r) ^ ((r) >> 3)) & 7)

    #define OSTAGE(C, BUF)                                                            \
        do {                                                                          \
            int hh_ = (C) >> 1, hf_ = (C) & 1;                                        \
            const uint4* gAh_ = (const uint4*)(AOh) +                                 \
                (((size_t)n * HEADS + hh_) * LSEQ + l0) * 8 + hf_ * 4;                \
            const uint4* gAl_ = (const uint4*)(AOl) +                                 \
                (((size_t)n * HEADS + hh_) * LSEQ + l0) * 8 + hf_ * 4;                \
            const uint4* gBh_ = (const uint4*)(Woh) +                                 \
                (size_t)e0 * 128 + hh_ * 8 + hf_ * 4;                                 \
            const uint4* gBl_ = (const uint4*)(Wol) +                                 \
                (size_t)e0 * 128 + hh_ * 8 + hf_ * 4;                                 \
            _Pragma("unroll")                                                         \
            for (int i_ = 0; i_ < 4; ++i_) {                                          \
                int s_ = t + 256 * i_;                                                \
                int row_ = s_ >> 3, sg_ = (s_ & 7) ^ SW(row_);                        \
                const uint4* src_ = (sg_ < 4 ? gAh_ : gAl_) +                         \
                    (size_t)row_ * 8 + (sg_ & 3);                                     \
                gload_lds16(src_, &sA[BUF][s_]);                                      \
            }                                                                         \
            _Pragma("unroll")                                                         \
            for (int i_ = 0; i_ < 2; ++i_) {                                          \
                int s_ = t + 256 * i_;                                                \
                int row_ = s_ >> 3, sg_ = (s_ & 7) ^ SW(row_);                        \
                const uint4* src_ = (sg_ < 4 ? gBh_ : gBl_) +                         \
                    (size_t)row_ * 128 + (sg_ & 3);                                   \
                gload_lds16(src_, &sB[BUF][s_]);                                      \
            }                                                                         \
        } while (0)

    f32x16 acc0, acc1;
    #pragma unroll
    for (int i = 0; i < 16; ++i) { acc0[i] = 0.f; acc1[i] = 0.f; }

    OSTAGE(0, 0);
    int cur = 0;

    const int amr = w * 32 + l5;                 // A fragment row (token), fixed
    const int swa  = SW(amr);                    // thread-invariant swizzles
    const int swb0 = SW(l5);
    const int swb1 = SW(32 + l5);

    for (int c = 0; c < 32; ++c) {
        if (c + 1 < 32) {
            OSTAGE(c + 1, cur ^ 1);
            asm volatile("s_waitcnt vmcnt(6)" ::: "memory");
        } else {
            asm volatile("s_waitcnt vmcnt(0)" ::: "memory");
        }
        __builtin_amdgcn_s_barrier();

        __builtin_amdgcn_s_setprio(1);
        #pragma unroll
        for (int ks = 0; ks < 2; ++ks) {
            int gx = ks * 2 + hi;
            bf16x8 ah  = as_bf16x8(sA[cur][amr * 8       + ( gx      ^ swa )]);
            bf16x8 al  = as_bf16x8(sA[cur][amr * 8       + ((gx + 4) ^ swa )]);
            bf16x8 bh0 = as_bf16x8(sB[cur][ l5       * 8 + ( gx      ^ swb0)]);
            bf16x8 bh1 = as_bf16x8(sB[cur][(32 + l5) * 8 + ( gx      ^ swb1)]);
            bf16x8 bl0 = as_bf16x8(sB[cur][ l5       * 8 + ((gx + 4) ^ swb0)]);
            bf16x8 bl1 = as_bf16x8(sB[cur][(32 + l5) * 8 + ((gx + 4) ^ swb1)]);

            acc0 = __builtin_amdgcn_mfma_f32_32x32x16_bf16(ah, bh0, acc0, 0, 0, 0);
            acc1 = __builtin_amdgcn_mfma_f32_32x32x16_bf16(ah, bh1, acc1, 0, 0, 0);
            acc0 = __builtin_amdgcn_mfma_f32_32x32x16_bf16(ah, bl0, acc0, 0, 0, 0);
            acc1 = __builtin_amdgcn_mfma_f32_32x32x16_bf16(ah, bl1, acc1, 0, 0, 0);
            acc0 = __builtin_amdgcn_mfma_f32_32x32x16_bf16(al, bh0, acc0, 0, 0, 0);
            acc1 = __builtin_amdgcn_mfma_f32_32x32x16_bf16(al, bh1, acc1, 0, 0, 0);
        }
        __builtin_amdgcn_s_setprio(0);
        __builtin_amdgcn_s_barrier();
        cur ^= 1;
    }
    #undef OSTAGE
    #undef SW

    float b0 = bo[e0 + l5];
    float b1 = bo[e0 + 32 + l5];
    #pragma unroll
    for (int r = 0; r < 16; ++r) {
        int row = m0 + w * 32 + (r & 3) + 8 * (r >> 2) + 4 * hi;
        float* o = out + (size_t)row * EMBED + e0;
        o[l5]      = acc0[r] + b0;
        o[32 + l5] = acc1[r] + b1;
    }
}

// ---------------------------------------------------------------------------
extern "C" void kernel_launch(void* const* d_in, const int* in_sizes, int n_in,
                              void* d_out, int out_size, void* d_ws, size_t ws_size,
                              hipStream_t stream)
{
    const float* values  = (const float*)d_in[0];
    const float* keys    = (const float*)d_in[1];
    const float* queries = (const float*)d_in[2];
    const float* Wv      = (const float*)d_in[3];
    const float* Wk      = (const float*)d_in[4];
    const float* Wq      = (const float*)d_in[5];
    const float* Wo      = (const float*)d_in[6];
    const float* bo      = (const float*)d_in[7];
    float* out = (float*)d_out;

    const size_t bufElems = (size_t)NB * HEADS * LSEQ * HD;   // 8,388,608
    unsigned short* Qp  = (unsigned short*)d_ws;
    unsigned short* Kp  = Qp  + bufElems;
    unsigned short* Vt  = Kp  + bufElems;
    unsigned short* AOh = Vt  + bufElems;
    unsigned short* AOl = AOh + bufElems;
    unsigned short* Woh = AOl + bufElems;
    unsigned short* Wol = Woh + (size_t)EMBED * EMBED;

    proj_kernel<<<dim3(NB * 8, HEADS, 4), 256, 0, stream>>>(
        values, keys, queries, Wv, Wk, Wq, Wo, Vt, Kp, Qp, Woh, Wol);
    attn_kernel<<<dim3(LSEQ / 128, HEADS, NB), 256, 0, stream>>>(Qp, Kp, Vt, AOh, AOl);
    outproj_kernel<<<dim3(NB * LSEQ / 128, EMBED / 64), 256, 0, stream>>>(AOh, AOl, Woh, Wol, bo, out);
}